// Round 14
// baseline (109.905 us; speedup 1.0000x reference)
//
#include <hip/hip_runtime.h>

#define NB 8
#define NS 2048
#define ND 64
#define LOG2E 1.44269504f

typedef _Float16 half8 __attribute__((ext_vector_type(8)));
typedef __attribute__((ext_vector_type(4))) float floatx4;

__device__ __forceinline__ half8 cvt8(const float* p) {
    float4 a = *(const float4*)p;
    float4 b = *(const float4*)(p + 4);
    half8 h = {(_Float16)a.x, (_Float16)a.y, (_Float16)a.z, (_Float16)a.w,
               (_Float16)b.x, (_Float16)b.y, (_Float16)b.z, (_Float16)b.w};
    return h;
}
__device__ __forceinline__ half8 cvtWcol(const float* base) {
    half8 h;
#pragma unroll
    for (int j = 0; j < 8; ++j) h[j] = (_Float16)base[j * 64];
    return h;
}

// ---------------- QKV projection via fp16 MFMA (r9 verbatim; XCD-aligned) -----
__global__ __launch_bounds__(256) void qkv_proj(
    const float* __restrict__ x,
    const float* __restrict__ Wq, const float* __restrict__ bq,
    const float* __restrict__ Wk, const float* __restrict__ bk,
    const float* __restrict__ Wv, const float* __restrict__ bv,
    _Float16* __restrict__ Qg, _Float16* __restrict__ Kg,
    _Float16* __restrict__ Vt)
{
    __shared__ _Float16 vt[64 * 18];

    const int tid  = threadIdx.x;
    const int wv   = tid >> 6;
    const int l    = tid & 63;
    const int quad = l >> 4;
    const int tx   = l & 15;

    const int b  = blockIdx.x & 7;
    const int n0 = (blockIdx.x >> 3) * 16;

    const float* xr = x + ((size_t)b * NS + n0 + tx) * ND + quad * 8;
    half8 a0 = cvt8(xr);
    half8 a1 = cvt8(xr + 32);

    const floatx4 zf = {0.f, 0.f, 0.f, 0.f};

#pragma unroll
    for (int i = 0; i < 3; ++i) {
        const int ct = wv * 3 + i;
        const int m  = ct >> 2;
        const int lcol = (ct & 3) * 16 + tx;

        const float* Wm;
        const float* Bm;
        if (m == 0)      { Wm = Wq; Bm = bq; }
        else if (m == 1) { Wm = Wk; Bm = bk; }
        else             { Wm = Wv; Bm = bv; }

        half8 b0 = cvtWcol(Wm + (quad * 8) * 64 + lcol);
        half8 b1 = cvtWcol(Wm + (32 + quad * 8) * 64 + lcol);

        floatx4 acc = __builtin_amdgcn_mfma_f32_16x16x32_f16(a0, b0, zf, 0, 0, 0);
        acc = __builtin_amdgcn_mfma_f32_16x16x32_f16(a1, b1, acc, 0, 0, 0);
        const float bias = Bm[lcol];

        if (m == 0) {
#pragma unroll
            for (int r = 0; r < 4; ++r)
                Qg[((size_t)b * NS + n0 + quad * 4 + r) * ND + lcol] =
                    (_Float16)((acc[r] + bias) * LOG2E);
        } else if (m == 1) {
#pragma unroll
            for (int r = 0; r < 4; ++r)
                Kg[((size_t)b * NS + n0 + quad * 4 + r) * ND + lcol] = (_Float16)(acc[r] + bias);
        } else {
#pragma unroll
            for (int r = 0; r < 4; ++r)
                vt[lcol * 18 + quad * 4 + r] = (_Float16)(acc[r] + bias);
        }
    }
    __syncthreads();
    {
        const int d = tid >> 2, seg = tid & 3;
        uint2 p = *(uint2*)&vt[d * 18 + seg * 4];
        *(uint2*)(Vt + ((size_t)b * ND + d) * NS + n0 + seg * 4) = p;
    }
}

// ---------------- fused masked attention: LDS-staged K/V, 2 blocks/CU --------
// grid: 512 blocks (b = blk&7 XCD-pinned, 32 q-rows), 512 thr = 8 waves =
// 2 q-halves (h: 16 rows) x 4 key-quarters (kq: 16 keys/tile; 16 dims in PV).
// K/V stream through double-buffered LDS tiles (64 keys, 76-half = 152B rows:
// 38 dwords -> bank 6*tx mod 32, all 16 lanes distinct -> conflict-free).
// 2 co-resident blocks/CU overlap each other's barrier drains.
// Pass 1: l = sum 2^s. Mask: e > l/N <=> p > mean(p) = 1/N. Pass 2: recompute
// s from LDS K, P -> LDS exchange, PV from LDS V^T; dims split by kq.
__global__ __launch_bounds__(512, 2) void attn(
    const _Float16* __restrict__ Qg,
    const _Float16* __restrict__ Kg,
    const _Float16* __restrict__ Vt,
    float* __restrict__ out)
{
    __shared__ _Float16 ksm[2 * 64 * 76];   // [buf][key][76]
    __shared__ _Float16 vsm[2 * 64 * 76];   // [buf][dim][76]  (V^T tile)
    __shared__ _Float16 psm[32 * 76];       // P exchange [row][76]
    __shared__ float lsh[128];              // per-kq row denominators (4 x 32)

    const int tid  = threadIdx.x;
    const int wv   = tid >> 6;
    const int l    = tid & 63;
    const int quad = l >> 4;
    const int tx   = l & 15;
    const int h    = wv >> 2;       // q-half (16 rows)
    const int kq   = wv & 3;        // key-quarter / dim-quarter

    const int b  = blockIdx.x & 7;
    const int q0 = (blockIdx.x >> 3) * 32;

    const _Float16* Qb = Qg + ((size_t)b * NS + q0 + h * 16) * ND;
    const _Float16* Kb = Kg + (size_t)b * NS * ND;
    const _Float16* Vb = Vt + (size_t)b * ND * NS;

    // Q A-frags: rows q0 + h*16 + tx, k-chunks 0/1
    half8 qf0 = *(const half8*)(Qb + (size_t)tx * ND + quad * 8);
    half8 qf1 = *(const half8*)(Qb + (size_t)tx * ND + 32 + quad * 8);

    // staging roles: thread -> 16B of the 8KB tile
    const int skey = tid >> 3;              // key (K) or dim (V)
    const int sc   = (tid & 7) * 8;         // half offset within row
    const _Float16* Ksrc = Kb + (size_t)skey * ND + sc;   // + t*64*ND
    const _Float16* Vsrc = Vb + (size_t)skey * NS + sc;   // + t*64
    const int sdst = skey * 76 + sc;

    const floatx4 zf = {0.f, 0.f, 0.f, 0.f};
    const int krow = (kq * 16 + tx) * 76;   // K/V fragment row base (halfs)

    // ================= pass 1: l = sum 2^s =================
    float lacc[4] = {0.f, 0.f, 0.f, 0.f};
    {
        uint4 gk = *(const uint4*)Ksrc;            // tile 0
        *(uint4*)(ksm + sdst) = gk;
        for (int t = 0; t < 32; ++t) {
            const int buf = (t & 1) * 4864;
            __syncthreads();                        // tile t staged & visible
            if (t < 31) gk = *(const uint4*)(Ksrc + (size_t)(t + 1) * 64 * ND);
            half8 kf0 = *(const half8*)(ksm + buf + krow + quad * 8);
            half8 kf1 = *(const half8*)(ksm + buf + krow + 32 + quad * 8);
            floatx4 c = __builtin_amdgcn_mfma_f32_16x16x32_f16(qf0, kf0, zf, 0, 0, 0);
            c = __builtin_amdgcn_mfma_f32_16x16x32_f16(qf1, kf1, c, 0, 0, 0);
#pragma unroll
            for (int r = 0; r < 4; ++r)
                lacc[r] += __builtin_amdgcn_exp2f(c[r]);
            if (t < 31) *(uint4*)(ksm + (buf ^ 4864) + sdst) = gk;
        }
    }
    // reduce over the 16 key-lanes; publish per (kq, row)
#pragma unroll
    for (int off = 1; off < 16; off <<= 1)
#pragma unroll
        for (int r = 0; r < 4; ++r)
            lacc[r] += __shfl_xor(lacc[r], off);
    if (tx == 0) {
#pragma unroll
        for (int r = 0; r < 4; ++r)
            lsh[kq * 32 + h * 16 + quad * 4 + r] = lacc[r];
    }

    // pass-2 tile-0 loads overlap the merge barrier
    uint4 gk2 = *(const uint4*)Ksrc;
    uint4 gv  = *(const uint4*)Vsrc;
    __syncthreads();                                // lsh ready; pass-1 LDS reads done

    float inv[4], thr[4];
#pragma unroll
    for (int r = 0; r < 4; ++r) {
        const int row = h * 16 + quad * 4 + r;
        float L = lsh[row] + lsh[32 + row] + lsh[64 + row] + lsh[96 + row];
        inv[r] = 1.f / L;
        thr[r] = L * (1.f / (float)NS);
    }

    // ================= pass 2: P + PV =================
    *(uint4*)(ksm + sdst) = gk2;
    *(uint4*)(vsm + sdst) = gv;
    floatx4 o = zf;

    for (int t = 0; t < 32; ++t) {
        const int buf = (t & 1) * 4864;
        __syncthreads();                            // B1: tiles staged; psm free
        if (t < 31) {
            gk2 = *(const uint4*)(Ksrc + (size_t)(t + 1) * 64 * ND);
            gv  = *(const uint4*)(Vsrc + (size_t)(t + 1) * 64);
        }
        // QK from LDS, mask+normalize, P -> psm
        half8 kf0 = *(const half8*)(ksm + buf + krow + quad * 8);
        half8 kf1 = *(const half8*)(ksm + buf + krow + 32 + quad * 8);
        floatx4 c = __builtin_amdgcn_mfma_f32_16x16x32_f16(qf0, kf0, zf, 0, 0, 0);
        c = __builtin_amdgcn_mfma_f32_16x16x32_f16(qf1, kf1, c, 0, 0, 0);
#pragma unroll
        for (int r = 0; r < 4; ++r) {
            float e = __builtin_amdgcn_exp2f(c[r]);
            float w = (e > thr[r]) ? e * inv[r] : 0.f;
            psm[(h * 16 + quad * 4 + r) * 76 + kq * 16 + tx] = (_Float16)w;
        }
        __syncthreads();                            // B2: psm complete
        // PV: A from psm (rows h*16+tx), B from vsm (dims kq*16+tx)
#pragma unroll
        for (int ck = 0; ck < 2; ++ck) {
            half8 vf = *(const half8*)(vsm + buf + krow + ck * 32 + quad * 8);
            half8 af = *(const half8*)(psm + (h * 16 + tx) * 76 + ck * 32 + quad * 8);
            o = __builtin_amdgcn_mfma_f32_16x16x32_f16(af, vf, o, 0, 0, 0);
        }
        if (t < 31) {
            *(uint4*)(ksm + (buf ^ 4864) + sdst) = gk2;
            *(uint4*)(vsm + (buf ^ 4864) + sdst) = gv;
        }
    }

    // store: wave owns rows q0+h*16.. x dims kq*16..+15 (C-layout), fp32
#pragma unroll
    for (int r = 0; r < 4; ++r)
        out[((size_t)b * NS + q0 + h * 16 + quad * 4 + r) * ND + kq * 16 + tx] = o[r];
}

extern "C" void kernel_launch(void* const* d_in, const int* in_sizes, int n_in,
                              void* d_out, int out_size, void* d_ws, size_t ws_size,
                              hipStream_t stream) {
    const float* x  = (const float*)d_in[0];
    const float* Wq = (const float*)d_in[1];
    const float* bq = (const float*)d_in[2];
    const float* Wk = (const float*)d_in[3];
    const float* bk = (const float*)d_in[4];
    const float* Wv = (const float*)d_in[5];
    const float* bv = (const float*)d_in[6];

    _Float16* Qg = (_Float16*)d_ws;
    _Float16* Kg = Qg + (size_t)NB * NS * ND;
    _Float16* Vt = Kg + (size_t)NB * NS * ND;

    qkv_proj<<<NB * (NS / 16), 256, 0, stream>>>(x, Wq, bq, Wk, bk, Wv, bv, Qg, Kg, Vt);
    attn<<<NB * (NS / 32), 512, 0, stream>>>(Qg, Kg, Vt, (float*)d_out);
}